// Round 1
// baseline (264.791 us; speedup 1.0000x reference)
//
#include <hip/hip_runtime.h>
#include <math.h>

#define BB 8
#define CC 64
#define NN 8192
#define KK 20
#define COUT 64
#define BN_EPS 1e-5

// ---------------------------------------------------------------------------
// Pass 1: yc[b][n][o], o in [0,128):
//   o <  64 : dot(wa[o], x[b][:,n])  with wa[o][c] = w[o][c] - w[o][64+c]
//   o >= 64 : dot(wb[o-64], x[b][:,n]) with wb[o][c] = w[o][64+c]
// Each thread owns one output channel o (its w-row lives in 64 VGPRs) and
// half of the 64-wide n tile. x tile staged transposed in LDS, consumed via
// uniform (broadcast) float4 reads.
// ---------------------------------------------------------------------------
__global__ __launch_bounds__(256) void pass1_yc(const float* __restrict__ x,
                                                const float* __restrict__ w,
                                                float* __restrict__ yc) {
    const int ntiles = NN / 64;
    const int b  = blockIdx.x / ntiles;
    const int n0 = (blockIdx.x % ntiles) * 64;
    const int t  = threadIdx.x;
    const int o    = t & 127;   // output channel 0..127
    const int half = t >> 7;    // 0/1 -> even/odd n within tile

    __shared__ float xs[64][68]; // xs[j][c] = x[b][c][n0+j]; row stride 272B (16B aligned)

    // stage x tile (transpose c-major -> n-major)
    {
        const int c  = t >> 4;  // 0..15
        const int j4 = t & 15;  // float4 index within row
        for (int cc = c; cc < 64; cc += 16) {
            float4 v = *reinterpret_cast<const float4*>(
                x + ((size_t)b * CC + cc) * NN + n0 + j4 * 4);
            xs[j4 * 4 + 0][cc] = v.x;
            xs[j4 * 4 + 1][cc] = v.y;
            xs[j4 * 4 + 2][cc] = v.z;
            xs[j4 * 4 + 3][cc] = v.w;
        }
    }

    // weight row into registers (L1-resident, 32 KB total)
    float wr[64];
    if (o < 64) {
#pragma unroll
        for (int c = 0; c < 64; ++c)
            wr[c] = w[o * 128 + c] - w[o * 128 + 64 + c];
    } else {
#pragma unroll
        for (int c = 0; c < 64; ++c)
            wr[c] = w[(o - 64) * 128 + 64 + c];
    }
    __syncthreads();

    for (int j = half; j < 64; j += 2) {
        float acc = 0.f;
#pragma unroll
        for (int c4 = 0; c4 < 16; ++c4) {
            float4 xv = *reinterpret_cast<const float4*>(&xs[j][c4 * 4]);
            acc = fmaf(wr[c4 * 4 + 0], xv.x, acc);
            acc = fmaf(wr[c4 * 4 + 1], xv.y, acc);
            acc = fmaf(wr[c4 * 4 + 2], xv.z, acc);
            acc = fmaf(wr[c4 * 4 + 3], xv.w, acc);
        }
        yc[((size_t)b * NN + n0 + j) * 128 + o] = acc; // coalesced (o fastest)
    }
}

// ---------------------------------------------------------------------------
// Pass 2: per (b,n,k): h[o] = yc[b][i1][o] + yc[b][i0][64+o]  (lane = o)
// Track per-(b,n,o) max/min over k; accumulate per-channel sum/sumsq into
// deterministic per-block partials (no float atomics).
// ---------------------------------------------------------------------------
__global__ __launch_bounds__(256) void pass2_gather(const float* __restrict__ yc,
                                                    const int* __restrict__ eidx,
                                                    float* __restrict__ hmm,
                                                    float* __restrict__ psum,
                                                    float* __restrict__ pssq) {
    const int tiles = NN / 32;
    const int b  = blockIdx.x / tiles;
    const int n0 = (blockIdx.x % tiles) * 32;
    const int w    = threadIdx.x >> 6;
    const int lane = threadIdx.x & 63;

    const int* e0 = eidx + (size_t)b * NN * KK;              // edge_index[0]
    const int* e1 = e0 + (size_t)BB * NN * KK;               // edge_index[1]
    const float* ycb = yc + (size_t)b * NN * 128;

    float sum = 0.f, ssq = 0.f;

    for (int i = 0; i < 8; ++i) {
        const int n = n0 + w * 8 + i;
        // wave-uniform index loads (20 ints = 5 x int4, 80B-aligned rows)
        int idx0[20], idx1[20];
        const int4* p0 = reinterpret_cast<const int4*>(e0 + (size_t)n * KK);
        const int4* p1 = reinterpret_cast<const int4*>(e1 + (size_t)n * KK);
#pragma unroll
        for (int q = 0; q < 5; ++q) {
            int4 a = p0[q];
            idx0[4 * q + 0] = a.x; idx0[4 * q + 1] = a.y;
            idx0[4 * q + 2] = a.z; idx0[4 * q + 3] = a.w;
            int4 c = p1[q];
            idx1[4 * q + 0] = c.x; idx1[4 * q + 1] = c.y;
            idx1[4 * q + 2] = c.z; idx1[4 * q + 3] = c.w;
        }
        float hmx = -3.402823466e38f, hmn = 3.402823466e38f;
#pragma unroll
        for (int k = 0; k < KK; ++k) {
            float v1 = ycb[(size_t)idx1[k] * 128 + lane];        // wa . x_i
            float v0 = ycb[(size_t)idx0[k] * 128 + 64 + lane];   // wb . x_j
            float h  = v1 + v0;
            hmx = fmaxf(hmx, h);
            hmn = fminf(hmn, h);
            sum += h;
            ssq = fmaf(h, h, ssq);
        }
        float* row = hmm + ((size_t)b * NN + n) * 128;
        row[lane]      = hmx;
        row[64 + lane] = hmn;
    }

    __shared__ float rs[4][64], rq[4][64];
    rs[w][lane] = sum;
    rq[w][lane] = ssq;
    __syncthreads();
    if (w == 0) {
        float s = rs[0][lane] + rs[1][lane] + rs[2][lane] + rs[3][lane];
        float q = rq[0][lane] + rq[1][lane] + rq[2][lane] + rq[3][lane];
        psum[(size_t)blockIdx.x * 64 + lane] = s;
        pssq[(size_t)blockIdx.x * 64 + lane] = q;
    }
}

// ---------------------------------------------------------------------------
// Pass 2b: deterministic reduction of block partials -> scale/shift per chan.
// ---------------------------------------------------------------------------
__global__ __launch_bounds__(256) void pass2b_stats(const float* __restrict__ psum,
                                                    const float* __restrict__ pssq,
                                                    const float* __restrict__ gamma,
                                                    const float* __restrict__ beta,
                                                    float* __restrict__ scsh,
                                                    int nblocks) {
    const int t = threadIdx.x;
    const int c = t & 63, s = t >> 6;
    double sum = 0.0, ssq = 0.0;
    for (int i = s; i < nblocks; i += 4) {   // coalesced rows per wave
        sum += (double)psum[(size_t)i * 64 + c];
        ssq += (double)pssq[(size_t)i * 64 + c];
    }
    __shared__ double ds_[4][64], dq_[4][64];
    ds_[s][c] = sum;
    dq_[s][c] = ssq;
    __syncthreads();
    if (s == 0) {
        double S = ds_[0][c] + ds_[1][c] + ds_[2][c] + ds_[3][c];
        double Q = dq_[0][c] + dq_[1][c] + dq_[2][c] + dq_[3][c];
        const double cnt = (double)BB * NN * KK;
        double mean = S / cnt;
        double var  = Q / cnt - mean * mean;
        float scale = (float)((double)gamma[c] / sqrt(var + BN_EPS));
        float shift = (float)((double)beta[c] - mean * (double)scale);
        scsh[c]      = scale;
        scsh[64 + c] = shift;
    }
}

// ---------------------------------------------------------------------------
// Pass 4: out[b][o][n] = relu(scale[o]*hsel + shift[o]),
//         hsel = scale>=0 ? hmax : hmin.  LDS transpose [n][o] -> [o][n].
// ---------------------------------------------------------------------------
__global__ __launch_bounds__(256) void pass4_out(const float* __restrict__ hmm,
                                                 const float* __restrict__ scsh,
                                                 float* __restrict__ out) {
    const int ntiles = NN / 64;
    const int b  = blockIdx.x / ntiles;
    const int n0 = (blockIdx.x % ntiles) * 64;
    const int w    = threadIdx.x >> 6;
    const int lane = threadIdx.x & 63;

    __shared__ float ts[64][65];
    const float sc = scsh[lane];
    const float sh = scsh[64 + lane];

    for (int i = 0; i < 16; ++i) {
        const int j = w + 4 * i;
        const float* row = hmm + ((size_t)b * NN + n0 + j) * 128;
        float hv = (sc >= 0.f) ? row[lane] : row[64 + lane];
        ts[j][lane] = fmaxf(0.f, fmaf(sc, hv, sh));
    }
    __syncthreads();
    for (int i = 0; i < 16; ++i) {
        const int o = w + 4 * i;
        out[((size_t)b * COUT + o) * NN + n0 + lane] = ts[lane][o];
    }
}

// ---------------------------------------------------------------------------
extern "C" void kernel_launch(void* const* d_in, const int* in_sizes, int n_in,
                              void* d_out, int out_size, void* d_ws, size_t ws_size,
                              hipStream_t stream) {
    const float* x     = (const float*)d_in[0]; // [B, C, N, 1]
    const float* wgt   = (const float*)d_in[1]; // [64, 128]
    const float* gamma = (const float*)d_in[2]; // [64]
    const float* beta  = (const float*)d_in[3]; // [64]
    const int*   eidx  = (const int*)d_in[4];   // [2, B, N, K]
    float* out = (float*)d_out;                 // [B, 64, N]

    // workspace layout (floats)
    float* yc   = (float*)d_ws;                         // B*N*128 = 8388608
    float* hmm  = yc + (size_t)BB * NN * 128;           // B*N*128 = 8388608
    float* psum = hmm + (size_t)BB * NN * 128;          // 2048*64
    float* pssq = psum + (size_t)(BB * (NN / 32)) * 64; // 2048*64
    float* scsh = pssq + (size_t)(BB * (NN / 32)) * 64; // 128

    const int nblk2 = BB * (NN / 32); // 2048

    hipLaunchKernelGGL(pass1_yc, dim3(BB * (NN / 64)), dim3(256), 0, stream,
                       x, wgt, yc);
    hipLaunchKernelGGL(pass2_gather, dim3(nblk2), dim3(256), 0, stream,
                       yc, eidx, hmm, psum, pssq);
    hipLaunchKernelGGL(pass2b_stats, dim3(1), dim3(256), 0, stream,
                       psum, pssq, gamma, beta, scsh, nblk2);
    hipLaunchKernelGGL(pass4_out, dim3(BB * (NN / 64)), dim3(256), 0, stream,
                       hmm, scsh, out);
}

// Round 2
// 140.151 us; speedup vs baseline: 1.8893x; 1.8893x over previous
//
#include <hip/hip_runtime.h>
#include <math.h>

#define BB 8
#define CC 64
#define NN 8192
#define KK 20
#define COUT 64
#define BN_EPS 1e-5

// ---------------------------------------------------------------------------
// Pass 1: yc[b][n][o], o in [0,128):
//   o <  64 : dot(wa[o], x[b][:,n])  with wa[o][c] = w[o][c] - w[o][64+c]
//   o >= 64 : dot(wb[o-64], x[b][:,n]) with wb[o][c] = w[o][64+c]
// ---------------------------------------------------------------------------
__global__ __launch_bounds__(256) void pass1_yc(const float* __restrict__ x,
                                                const float* __restrict__ w,
                                                float* __restrict__ yc) {
    const int ntiles = NN / 64;
    const int b  = blockIdx.x / ntiles;
    const int n0 = (blockIdx.x % ntiles) * 64;
    const int t  = threadIdx.x;
    const int o    = t & 127;   // output channel 0..127
    const int half = t >> 7;    // 0/1 -> even/odd n within tile

    __shared__ float xs[64][68]; // xs[j][c] = x[b][c][n0+j]

    // stage x tile (transpose c-major -> n-major)
    {
        const int c  = t >> 4;  // 0..15
        const int j4 = t & 15;  // float4 index within row
        for (int cc = c; cc < 64; cc += 16) {
            float4 v = *reinterpret_cast<const float4*>(
                x + ((size_t)b * CC + cc) * NN + n0 + j4 * 4);
            xs[j4 * 4 + 0][cc] = v.x;
            xs[j4 * 4 + 1][cc] = v.y;
            xs[j4 * 4 + 2][cc] = v.z;
            xs[j4 * 4 + 3][cc] = v.w;
        }
    }

    // weight row into registers
    float wr[64];
    if (o < 64) {
#pragma unroll
        for (int c = 0; c < 64; ++c)
            wr[c] = w[o * 128 + c] - w[o * 128 + 64 + c];
    } else {
#pragma unroll
        for (int c = 0; c < 64; ++c)
            wr[c] = w[(o - 64) * 128 + 64 + c];
    }
    __syncthreads();

    for (int j = half; j < 64; j += 2) {
        float acc = 0.f;
#pragma unroll
        for (int c4 = 0; c4 < 16; ++c4) {
            float4 xv = *reinterpret_cast<const float4*>(&xs[j][c4 * 4]);
            acc = fmaf(wr[c4 * 4 + 0], xv.x, acc);
            acc = fmaf(wr[c4 * 4 + 1], xv.y, acc);
            acc = fmaf(wr[c4 * 4 + 2], xv.z, acc);
            acc = fmaf(wr[c4 * 4 + 3], xv.w, acc);
        }
        yc[((size_t)b * NN + n0 + j) * 128 + o] = acc;
    }
}

// ---------------------------------------------------------------------------
// Pass 2: per (b,n,k): h[o] = yc[b][i1][o] + yc[b][i0][64+o]  (lane = o)
// ---------------------------------------------------------------------------
__global__ __launch_bounds__(256) void pass2_gather(const float* __restrict__ yc,
                                                    const int* __restrict__ eidx,
                                                    float* __restrict__ hmm,
                                                    float* __restrict__ psum,
                                                    float* __restrict__ pssq) {
    const int tiles = NN / 32;
    const int b  = blockIdx.x / tiles;
    const int n0 = (blockIdx.x % tiles) * 32;
    const int w    = threadIdx.x >> 6;
    const int lane = threadIdx.x & 63;

    const int* e0 = eidx + (size_t)b * NN * KK;              // edge_index[0]
    const int* e1 = e0 + (size_t)BB * NN * KK;               // edge_index[1]
    const float* ycb = yc + (size_t)b * NN * 128;

    float sum = 0.f, ssq = 0.f;

    for (int i = 0; i < 8; ++i) {
        const int n = n0 + w * 8 + i;
        int idx0[20], idx1[20];
        const int4* p0 = reinterpret_cast<const int4*>(e0 + (size_t)n * KK);
        const int4* p1 = reinterpret_cast<const int4*>(e1 + (size_t)n * KK);
#pragma unroll
        for (int q = 0; q < 5; ++q) {
            int4 a = p0[q];
            idx0[4 * q + 0] = a.x; idx0[4 * q + 1] = a.y;
            idx0[4 * q + 2] = a.z; idx0[4 * q + 3] = a.w;
            int4 c = p1[q];
            idx1[4 * q + 0] = c.x; idx1[4 * q + 1] = c.y;
            idx1[4 * q + 2] = c.z; idx1[4 * q + 3] = c.w;
        }
        float hmx = -3.402823466e38f, hmn = 3.402823466e38f;
#pragma unroll
        for (int k = 0; k < KK; ++k) {
            float v1 = ycb[(size_t)idx1[k] * 128 + lane];        // wa . x_i
            float v0 = ycb[(size_t)idx0[k] * 128 + 64 + lane];   // wb . x_j
            float h  = v1 + v0;
            hmx = fmaxf(hmx, h);
            hmn = fminf(hmn, h);
            sum += h;
            ssq = fmaf(h, h, ssq);
        }
        float* row = hmm + ((size_t)b * NN + n) * 128;
        row[lane]      = hmx;
        row[64 + lane] = hmn;
    }

    __shared__ float rs[4][64], rq[4][64];
    rs[w][lane] = sum;
    rq[w][lane] = ssq;
    __syncthreads();
    if (w == 0) {
        float s = rs[0][lane] + rs[1][lane] + rs[2][lane] + rs[3][lane];
        float q = rq[0][lane] + rq[1][lane] + rq[2][lane] + rq[3][lane];
        psum[(size_t)blockIdx.x * 64 + lane] = s;
        pssq[(size_t)blockIdx.x * 64 + lane] = q;
    }
}

// ---------------------------------------------------------------------------
// Pass 2b stage 1: 32 blocks, each reduces 64 of the 2048 partial rows
// (coalesced: 4 consecutive rows per 256-thread read). Deterministic order.
// ---------------------------------------------------------------------------
__global__ __launch_bounds__(256) void pass2b_stage1(const float* __restrict__ psum,
                                                     const float* __restrict__ pssq,
                                                     double* __restrict__ p2sum,
                                                     double* __restrict__ p2ssq,
                                                     int nblocks) {
    const int t = threadIdx.x;
    const int c = t & 63, s = t >> 6;
    double sum = 0.0, ssq = 0.0;
    for (int i = blockIdx.x * 4 + s; i < nblocks; i += 32 * 4) {
        sum += (double)psum[(size_t)i * 64 + c];
        ssq += (double)pssq[(size_t)i * 64 + c];
    }
    __shared__ double ds_[4][64], dq_[4][64];
    ds_[s][c] = sum;
    dq_[s][c] = ssq;
    __syncthreads();
    if (s == 0) {
        p2sum[(size_t)blockIdx.x * 64 + c] = ds_[0][c] + ds_[1][c] + ds_[2][c] + ds_[3][c];
        p2ssq[(size_t)blockIdx.x * 64 + c] = dq_[0][c] + dq_[1][c] + dq_[2][c] + dq_[3][c];
    }
}

// ---------------------------------------------------------------------------
// Pass 2b stage 2: single tiny block reduces 32 rows -> scale/shift.
// ---------------------------------------------------------------------------
__global__ __launch_bounds__(256) void pass2b_stage2(const double* __restrict__ p2sum,
                                                     const double* __restrict__ p2ssq,
                                                     const float* __restrict__ gamma,
                                                     const float* __restrict__ beta,
                                                     float* __restrict__ scsh) {
    const int t = threadIdx.x;
    const int c = t & 63, s = t >> 6;
    double sum = 0.0, ssq = 0.0;
    for (int i = s; i < 32; i += 4) {
        sum += p2sum[(size_t)i * 64 + c];
        ssq += p2ssq[(size_t)i * 64 + c];
    }
    __shared__ double ds_[4][64], dq_[4][64];
    ds_[s][c] = sum;
    dq_[s][c] = ssq;
    __syncthreads();
    if (s == 0) {
        double S = ds_[0][c] + ds_[1][c] + ds_[2][c] + ds_[3][c];
        double Q = dq_[0][c] + dq_[1][c] + dq_[2][c] + dq_[3][c];
        const double cnt = (double)BB * NN * KK;
        double mean = S / cnt;
        double var  = Q / cnt - mean * mean;
        float scale = (float)((double)gamma[c] / sqrt(var + BN_EPS));
        float shift = (float)((double)beta[c] - mean * (double)scale);
        scsh[c]      = scale;
        scsh[64 + c] = shift;
    }
}

// ---------------------------------------------------------------------------
// Pass 4: out[b][o][n] = relu(scale[o]*hsel + shift[o])
// ---------------------------------------------------------------------------
__global__ __launch_bounds__(256) void pass4_out(const float* __restrict__ hmm,
                                                 const float* __restrict__ scsh,
                                                 float* __restrict__ out) {
    const int ntiles = NN / 64;
    const int b  = blockIdx.x / ntiles;
    const int n0 = (blockIdx.x % ntiles) * 64;
    const int w    = threadIdx.x >> 6;
    const int lane = threadIdx.x & 63;

    __shared__ float ts[64][65];
    const float sc = scsh[lane];
    const float sh = scsh[64 + lane];

    for (int i = 0; i < 16; ++i) {
        const int j = w + 4 * i;
        const float* row = hmm + ((size_t)b * NN + n0 + j) * 128;
        float hv = (sc >= 0.f) ? row[lane] : row[64 + lane];
        ts[j][lane] = fmaxf(0.f, fmaf(sc, hv, sh));
    }
    __syncthreads();
    for (int i = 0; i < 16; ++i) {
        const int o = w + 4 * i;
        out[((size_t)b * COUT + o) * NN + n0 + lane] = ts[lane][o];
    }
}

// ---------------------------------------------------------------------------
extern "C" void kernel_launch(void* const* d_in, const int* in_sizes, int n_in,
                              void* d_out, int out_size, void* d_ws, size_t ws_size,
                              hipStream_t stream) {
    const float* x     = (const float*)d_in[0]; // [B, C, N, 1]
    const float* wgt   = (const float*)d_in[1]; // [64, 128]
    const float* gamma = (const float*)d_in[2]; // [64]
    const float* beta  = (const float*)d_in[3]; // [64]
    const int*   eidx  = (const int*)d_in[4];   // [2, B, N, K]
    float* out = (float*)d_out;                 // [B, 64, N]

    // workspace layout
    float* yc   = (float*)d_ws;                         // B*N*128 floats
    float* hmm  = yc + (size_t)BB * NN * 128;           // B*N*128 floats
    float* psum = hmm + (size_t)BB * NN * 128;          // 2048*64 floats
    float* pssq = psum + (size_t)(BB * (NN / 32)) * 64; // 2048*64 floats
    float* scsh = pssq + (size_t)(BB * (NN / 32)) * 64; // 128 floats
    double* p2sum = (double*)(scsh + 128 + 32);         // 32*64 doubles (8B aligned)
    double* p2ssq = p2sum + 32 * 64;                    // 32*64 doubles

    const int nblk2 = BB * (NN / 32); // 2048

    hipLaunchKernelGGL(pass1_yc, dim3(BB * (NN / 64)), dim3(256), 0, stream,
                       x, wgt, yc);
    hipLaunchKernelGGL(pass2_gather, dim3(nblk2), dim3(256), 0, stream,
                       yc, eidx, hmm, psum, pssq);
    hipLaunchKernelGGL(pass2b_stage1, dim3(32), dim3(256), 0, stream,
                       psum, pssq, p2sum, p2ssq, nblk2);
    hipLaunchKernelGGL(pass2b_stage2, dim3(1), dim3(256), 0, stream,
                       p2sum, p2ssq, gamma, beta, scsh);
    hipLaunchKernelGGL(pass4_out, dim3(BB * (NN / 64)), dim3(256), 0, stream,
                       hmm, scsh, out);
}

// Round 3
// 111.996 us; speedup vs baseline: 2.3643x; 1.2514x over previous
//
#include <hip/hip_runtime.h>
#include <math.h>

#define BB 8
#define CC 64
#define NN 8192
#define KK 20
#define COUT 64
#define BN_EPS 1e-5

// XCD swizzle: MI355X dispatches blockIdx round-robin over 8 XCDs, so
// (blockIdx.x & 7) == XCD id.  Putting batch b on XCD b makes b's 4 MB yc
// slice resident in that XCD's 4 MiB L2 for the random-row gathers.

// ---------------------------------------------------------------------------
// Pass 1: yc[b][n][o], o in [0,128):
//   o <  64 : dot(wa[o], x[b][:,n])  with wa[o][c] = w[o][c] - w[o][64+c]
//   o >= 64 : dot(wb[o-64], x[b][:,n]) with wb[o][c] = w[o][64+c]
// ---------------------------------------------------------------------------
__global__ __launch_bounds__(256) void pass1_yc(const float* __restrict__ x,
                                                const float* __restrict__ w,
                                                float* __restrict__ yc) {
    const int b  = blockIdx.x & 7;          // XCD-aligned batch
    const int n0 = (blockIdx.x >> 3) * 64;
    const int t  = threadIdx.x;
    const int o    = t & 127;   // output channel 0..127
    const int half = t >> 7;    // 0/1 -> even/odd n within tile

    __shared__ float xs[64][68]; // xs[j][c] = x[b][c][n0+j]

    // stage x tile (transpose c-major -> n-major)
    {
        const int c  = t >> 4;  // 0..15
        const int j4 = t & 15;  // float4 index within row
        for (int cc = c; cc < 64; cc += 16) {
            float4 v = *reinterpret_cast<const float4*>(
                x + ((size_t)b * CC + cc) * NN + n0 + j4 * 4);
            xs[j4 * 4 + 0][cc] = v.x;
            xs[j4 * 4 + 1][cc] = v.y;
            xs[j4 * 4 + 2][cc] = v.z;
            xs[j4 * 4 + 3][cc] = v.w;
        }
    }

    // weight row into registers
    float wr[64];
    if (o < 64) {
#pragma unroll
        for (int c = 0; c < 64; ++c)
            wr[c] = w[o * 128 + c] - w[o * 128 + 64 + c];
    } else {
#pragma unroll
        for (int c = 0; c < 64; ++c)
            wr[c] = w[(o - 64) * 128 + 64 + c];
    }
    __syncthreads();

    for (int j = half; j < 64; j += 2) {
        float acc = 0.f;
#pragma unroll
        for (int c4 = 0; c4 < 16; ++c4) {
            float4 xv = *reinterpret_cast<const float4*>(&xs[j][c4 * 4]);
            acc = fmaf(wr[c4 * 4 + 0], xv.x, acc);
            acc = fmaf(wr[c4 * 4 + 1], xv.y, acc);
            acc = fmaf(wr[c4 * 4 + 2], xv.z, acc);
            acc = fmaf(wr[c4 * 4 + 3], xv.w, acc);
        }
        yc[((size_t)b * NN + n0 + j) * 128 + o] = acc;
    }
}

// ---------------------------------------------------------------------------
// Pass 2: per (b,n,k): h[o] = yc[b][i1][o] + yc[b][i0][64+o]  (lane = o)
// ---------------------------------------------------------------------------
__global__ __launch_bounds__(256) void pass2_gather(const float* __restrict__ yc,
                                                    const int* __restrict__ eidx,
                                                    float* __restrict__ hmm,
                                                    float* __restrict__ psum,
                                                    float* __restrict__ pssq) {
    const int b  = blockIdx.x & 7;          // XCD-aligned batch
    const int n0 = (blockIdx.x >> 3) * 32;
    const int w    = threadIdx.x >> 6;
    const int lane = threadIdx.x & 63;

    const int* e0 = eidx + (size_t)b * NN * KK;              // edge_index[0]
    const int* e1 = e0 + (size_t)BB * NN * KK;               // edge_index[1]
    const float* ycb = yc + (size_t)b * NN * 128;

    float sum = 0.f, ssq = 0.f;

    for (int i = 0; i < 8; ++i) {
        const int n = n0 + w * 8 + i;
        int idx0[20], idx1[20];
        const int4* p0 = reinterpret_cast<const int4*>(e0 + (size_t)n * KK);
        const int4* p1 = reinterpret_cast<const int4*>(e1 + (size_t)n * KK);
#pragma unroll
        for (int q = 0; q < 5; ++q) {
            int4 a = p0[q];
            idx0[4 * q + 0] = a.x; idx0[4 * q + 1] = a.y;
            idx0[4 * q + 2] = a.z; idx0[4 * q + 3] = a.w;
            int4 c = p1[q];
            idx1[4 * q + 0] = c.x; idx1[4 * q + 1] = c.y;
            idx1[4 * q + 2] = c.z; idx1[4 * q + 3] = c.w;
        }
        float hmx = -3.402823466e38f, hmn = 3.402823466e38f;
#pragma unroll
        for (int k = 0; k < KK; ++k) {
            float v1 = ycb[(size_t)idx1[k] * 128 + lane];        // wa . x_i
            float v0 = ycb[(size_t)idx0[k] * 128 + 64 + lane];   // wb . x_j
            float h  = v1 + v0;
            hmx = fmaxf(hmx, h);
            hmn = fminf(hmn, h);
            sum += h;
            ssq = fmaf(h, h, ssq);
        }
        float* row = hmm + ((size_t)b * NN + n) * 128;
        row[lane]      = hmx;
        row[64 + lane] = hmn;
    }

    __shared__ float rs[4][64], rq[4][64];
    rs[w][lane] = sum;
    rq[w][lane] = ssq;
    __syncthreads();
    if (w == 0) {
        float s = rs[0][lane] + rs[1][lane] + rs[2][lane] + rs[3][lane];
        float q = rq[0][lane] + rq[1][lane] + rq[2][lane] + rq[3][lane];
        psum[(size_t)blockIdx.x * 64 + lane] = s;
        pssq[(size_t)blockIdx.x * 64 + lane] = q;
    }
}

// ---------------------------------------------------------------------------
// Pass 2b stage 1: 32 blocks, each reduces 64 of the 2048 partial rows.
// ---------------------------------------------------------------------------
__global__ __launch_bounds__(256) void pass2b_stage1(const float* __restrict__ psum,
                                                     const float* __restrict__ pssq,
                                                     double* __restrict__ p2sum,
                                                     double* __restrict__ p2ssq,
                                                     int nblocks) {
    const int t = threadIdx.x;
    const int c = t & 63, s = t >> 6;
    double sum = 0.0, ssq = 0.0;
    for (int i = blockIdx.x * 4 + s; i < nblocks; i += 32 * 4) {
        sum += (double)psum[(size_t)i * 64 + c];
        ssq += (double)pssq[(size_t)i * 64 + c];
    }
    __shared__ double ds_[4][64], dq_[4][64];
    ds_[s][c] = sum;
    dq_[s][c] = ssq;
    __syncthreads();
    if (s == 0) {
        p2sum[(size_t)blockIdx.x * 64 + c] = ds_[0][c] + ds_[1][c] + ds_[2][c] + ds_[3][c];
        p2ssq[(size_t)blockIdx.x * 64 + c] = dq_[0][c] + dq_[1][c] + dq_[2][c] + dq_[3][c];
    }
}

// ---------------------------------------------------------------------------
// Pass 2b stage 2: single tiny block reduces 32 rows -> scale/shift.
// ---------------------------------------------------------------------------
__global__ __launch_bounds__(256) void pass2b_stage2(const double* __restrict__ p2sum,
                                                     const double* __restrict__ p2ssq,
                                                     const float* __restrict__ gamma,
                                                     const float* __restrict__ beta,
                                                     float* __restrict__ scsh) {
    const int t = threadIdx.x;
    const int c = t & 63, s = t >> 6;
    double sum = 0.0, ssq = 0.0;
    for (int i = s; i < 32; i += 4) {
        sum += p2sum[(size_t)i * 64 + c];
        ssq += p2ssq[(size_t)i * 64 + c];
    }
    __shared__ double ds_[4][64], dq_[4][64];
    ds_[s][c] = sum;
    dq_[s][c] = ssq;
    __syncthreads();
    if (s == 0) {
        double S = ds_[0][c] + ds_[1][c] + ds_[2][c] + ds_[3][c];
        double Q = dq_[0][c] + dq_[1][c] + dq_[2][c] + dq_[3][c];
        const double cnt = (double)BB * NN * KK;
        double mean = S / cnt;
        double var  = Q / cnt - mean * mean;
        float scale = (float)((double)gamma[c] / sqrt(var + BN_EPS));
        float shift = (float)((double)beta[c] - mean * (double)scale);
        scsh[c]      = scale;
        scsh[64 + c] = shift;
    }
}

// ---------------------------------------------------------------------------
// Pass 4: out[b][o][n] = relu(scale[o]*hsel + shift[o])
// ---------------------------------------------------------------------------
__global__ __launch_bounds__(256) void pass4_out(const float* __restrict__ hmm,
                                                 const float* __restrict__ scsh,
                                                 float* __restrict__ out) {
    const int b  = blockIdx.x & 7;          // XCD-aligned batch (hmm locality)
    const int n0 = (blockIdx.x >> 3) * 64;
    const int w    = threadIdx.x >> 6;
    const int lane = threadIdx.x & 63;

    __shared__ float ts[64][65];
    const float sc = scsh[lane];
    const float sh = scsh[64 + lane];

    for (int i = 0; i < 16; ++i) {
        const int j = w + 4 * i;
        const float* row = hmm + ((size_t)b * NN + n0 + j) * 128;
        float hv = (sc >= 0.f) ? row[lane] : row[64 + lane];
        ts[j][lane] = fmaxf(0.f, fmaf(sc, hv, sh));
    }
    __syncthreads();
    for (int i = 0; i < 16; ++i) {
        const int o = w + 4 * i;
        out[((size_t)b * COUT + o) * NN + n0 + lane] = ts[lane][o];
    }
}

// ---------------------------------------------------------------------------
extern "C" void kernel_launch(void* const* d_in, const int* in_sizes, int n_in,
                              void* d_out, int out_size, void* d_ws, size_t ws_size,
                              hipStream_t stream) {
    const float* x     = (const float*)d_in[0]; // [B, C, N, 1]
    const float* wgt   = (const float*)d_in[1]; // [64, 128]
    const float* gamma = (const float*)d_in[2]; // [64]
    const float* beta  = (const float*)d_in[3]; // [64]
    const int*   eidx  = (const int*)d_in[4];   // [2, B, N, K]
    float* out = (float*)d_out;                 // [B, 64, N]

    // workspace layout
    float* yc   = (float*)d_ws;                         // B*N*128 floats
    float* hmm  = yc + (size_t)BB * NN * 128;           // B*N*128 floats
    float* psum = hmm + (size_t)BB * NN * 128;          // 2048*64 floats
    float* pssq = psum + (size_t)(BB * (NN / 32)) * 64; // 2048*64 floats
    float* scsh = pssq + (size_t)(BB * (NN / 32)) * 64; // 128 floats
    double* p2sum = (double*)(scsh + 128 + 32);         // 32*64 doubles
    double* p2ssq = p2sum + 32 * 64;                    // 32*64 doubles

    const int nblk2 = BB * (NN / 32); // 2048

    hipLaunchKernelGGL(pass1_yc, dim3(BB * (NN / 64)), dim3(256), 0, stream,
                       x, wgt, yc);
    hipLaunchKernelGGL(pass2_gather, dim3(nblk2), dim3(256), 0, stream,
                       yc, eidx, hmm, psum, pssq);
    hipLaunchKernelGGL(pass2b_stage1, dim3(32), dim3(256), 0, stream,
                       psum, pssq, p2sum, p2ssq, nblk2);
    hipLaunchKernelGGL(pass2b_stage2, dim3(1), dim3(256), 0, stream,
                       p2sum, p2ssq, gamma, beta, scsh);
    hipLaunchKernelGGL(pass4_out, dim3(BB * (NN / 64)), dim3(256), 0, stream,
                       hmm, scsh, out);
}

// Round 5
// 101.870 us; speedup vs baseline: 2.5993x; 1.0994x over previous
//
#include <hip/hip_runtime.h>
#include <hip/hip_fp16.h>
#include <math.h>

#define BB 8
#define CC 64
#define NN 8192
#define KK 20
#define COUT 64
#define BN_EPS 1e-5

// XCD swizzle: blockIdx round-robins over 8 XCDs, so (blockIdx.x & 7) == XCD.
// Batch b pinned to XCD b keeps b's 4 MB yc slice resident in that XCD's L2.

// ---------------------------------------------------------------------------
// Pass 1: yc[b][n][o], o in [0,128):
//   o <  64 : dot(wa[o], x)  with wa[o][c] = w[o][c] - w[o][64+c]
//   o >= 64 : dot(wb[o-64], x) with wb[o][c] = w[o][64+c]
// ---------------------------------------------------------------------------
__global__ __launch_bounds__(256) void pass1_yc(const float* __restrict__ x,
                                                const float* __restrict__ w,
                                                float* __restrict__ yc) {
    const int b  = blockIdx.x & 7;
    const int n0 = (blockIdx.x >> 3) * 64;
    const int t  = threadIdx.x;
    const int o    = t & 127;
    const int half = t >> 7;

    __shared__ float xs[64][68]; // xs[j][c] = x[b][c][n0+j]

    {
        const int c  = t >> 4;
        const int j4 = t & 15;
        for (int cc = c; cc < 64; cc += 16) {
            float4 v = *reinterpret_cast<const float4*>(
                x + ((size_t)b * CC + cc) * NN + n0 + j4 * 4);
            xs[j4 * 4 + 0][cc] = v.x;
            xs[j4 * 4 + 1][cc] = v.y;
            xs[j4 * 4 + 2][cc] = v.z;
            xs[j4 * 4 + 3][cc] = v.w;
        }
    }

    float wr[64];
    if (o < 64) {
#pragma unroll
        for (int c = 0; c < 64; ++c)
            wr[c] = w[o * 128 + c] - w[o * 128 + 64 + c];
    } else {
#pragma unroll
        for (int c = 0; c < 64; ++c)
            wr[c] = w[(o - 64) * 128 + 64 + c];
    }
    __syncthreads();

    for (int j = half; j < 64; j += 2) {
        float acc = 0.f;
#pragma unroll
        for (int c4 = 0; c4 < 16; ++c4) {
            float4 xv = *reinterpret_cast<const float4*>(&xs[j][c4 * 4]);
            acc = fmaf(wr[c4 * 4 + 0], xv.x, acc);
            acc = fmaf(wr[c4 * 4 + 1], xv.y, acc);
            acc = fmaf(wr[c4 * 4 + 2], xv.z, acc);
            acc = fmaf(wr[c4 * 4 + 3], xv.w, acc);
        }
        yc[((size_t)b * NN + n0 + j) * 128 + o] = acc;
    }
}

// ---------------------------------------------------------------------------
// Pass 2 (float4-gather version).
// Lane layout: g = lane>>4 (k-slot), q = lane&15 (channel quad).
// Per n: 10 scalar idx loads + 10 float4 gathers.
// hmm stored as fp16: row = [64 x max][64 x min] halves (256 B).
// ---------------------------------------------------------------------------
__global__ __launch_bounds__(256, 6) void pass2_gather(const float* __restrict__ yc,
                                                       const int* __restrict__ eidx,
                                                       __half* __restrict__ hmm,
                                                       float* __restrict__ psum,
                                                       float* __restrict__ pssq) {
    const int b  = blockIdx.x & 7;
    const int n0 = (blockIdx.x >> 3) * 32;
    const int w    = threadIdx.x >> 6;
    const int lane = threadIdx.x & 63;
    const int g = lane >> 4;   // k-slot 0..3
    const int q = lane & 15;   // channel quad

    const int* e0 = eidx + (size_t)b * NN * KK;   // edge_index[0]
    const int* e1 = e0 + (size_t)BB * NN * KK;    // edge_index[1]
    const float* yca = yc + (size_t)b * NN * 128 + 4 * q;        // wa half
    const float* ycb = yc + (size_t)b * NN * 128 + 64 + 4 * q;   // wb half

    float4 sum4 = {0.f, 0.f, 0.f, 0.f};
    float4 ssq4 = {0.f, 0.f, 0.f, 0.f};

    for (int i = 0; i < 8; ++i) {
        const int n = n0 + w * 8 + i;
        const int* r1 = e1 + (size_t)n * KK;
        const int* r0 = e0 + (size_t)n * KK;
        // this lane's k indices: k = 4*s + g, s = 0..4
        int i1k[5], i0k[5];
#pragma unroll
        for (int s = 0; s < 5; ++s) {
            i1k[s] = r1[4 * s + g];
            i0k[s] = r0[4 * s + g];
        }
        float4 mx = {-3.402823466e38f, -3.402823466e38f, -3.402823466e38f, -3.402823466e38f};
        float4 mn = { 3.402823466e38f,  3.402823466e38f,  3.402823466e38f,  3.402823466e38f};
#pragma unroll
        for (int s = 0; s < 5; ++s) {
            float4 v1 = *reinterpret_cast<const float4*>(yca + (size_t)i1k[s] * 128);
            float4 v0 = *reinterpret_cast<const float4*>(ycb + (size_t)i0k[s] * 128);
            float4 h;
            h.x = v1.x + v0.x; h.y = v1.y + v0.y;
            h.z = v1.z + v0.z; h.w = v1.w + v0.w;
            mx.x = fmaxf(mx.x, h.x); mx.y = fmaxf(mx.y, h.y);
            mx.z = fmaxf(mx.z, h.z); mx.w = fmaxf(mx.w, h.w);
            mn.x = fminf(mn.x, h.x); mn.y = fminf(mn.y, h.y);
            mn.z = fminf(mn.z, h.z); mn.w = fminf(mn.w, h.w);
            sum4.x += h.x; sum4.y += h.y; sum4.z += h.z; sum4.w += h.w;
            ssq4.x = fmaf(h.x, h.x, ssq4.x); ssq4.y = fmaf(h.y, h.y, ssq4.y);
            ssq4.z = fmaf(h.z, h.z, ssq4.z); ssq4.w = fmaf(h.w, h.w, ssq4.w);
        }
        // merge the 4 k-subsets (groups) via butterfly
#pragma unroll
        for (int m = 16; m <= 32; m <<= 1) {
            mx.x = fmaxf(mx.x, __shfl_xor(mx.x, m));
            mx.y = fmaxf(mx.y, __shfl_xor(mx.y, m));
            mx.z = fmaxf(mx.z, __shfl_xor(mx.z, m));
            mx.w = fmaxf(mx.w, __shfl_xor(mx.w, m));
            mn.x = fminf(mn.x, __shfl_xor(mn.x, m));
            mn.y = fminf(mn.y, __shfl_xor(mn.y, m));
            mn.z = fminf(mn.z, __shfl_xor(mn.z, m));
            mn.w = fminf(mn.w, __shfl_xor(mn.w, m));
        }
        if (g < 2) {
            float4 v = (g == 0) ? mx : mn;
            __half2 pa = __floats2half2_rn(v.x, v.y);
            __half2 pb = __floats2half2_rn(v.z, v.w);
            uint2 pk;
            pk.x = *reinterpret_cast<unsigned*>(&pa);
            pk.y = *reinterpret_cast<unsigned*>(&pb);
            *reinterpret_cast<uint2*>(hmm + ((size_t)b * NN + n) * 128 + g * 64 + 4 * q) = pk;
        }
    }

    // cross-group sum/ssq reduce (once per block)
#pragma unroll
    for (int m = 16; m <= 32; m <<= 1) {
        sum4.x += __shfl_xor(sum4.x, m); sum4.y += __shfl_xor(sum4.y, m);
        sum4.z += __shfl_xor(sum4.z, m); sum4.w += __shfl_xor(sum4.w, m);
        ssq4.x += __shfl_xor(ssq4.x, m); ssq4.y += __shfl_xor(ssq4.y, m);
        ssq4.z += __shfl_xor(ssq4.z, m); ssq4.w += __shfl_xor(ssq4.w, m);
    }
    __shared__ float rs[4][64], rq[4][64];
    if (g == 0) {
        *reinterpret_cast<float4*>(&rs[w][4 * q]) = sum4;
        *reinterpret_cast<float4*>(&rq[w][4 * q]) = ssq4;
    }
    __syncthreads();
    if (w == 0) {
        float s = rs[0][lane] + rs[1][lane] + rs[2][lane] + rs[3][lane];
        float qq = rq[0][lane] + rq[1][lane] + rq[2][lane] + rq[3][lane];
        psum[(size_t)blockIdx.x * 64 + lane] = s;
        pssq[(size_t)blockIdx.x * 64 + lane] = qq;
    }
}

// ---------------------------------------------------------------------------
// Pass 2b stage 1: 32 blocks reduce the 2048 partial rows.
// ---------------------------------------------------------------------------
__global__ __launch_bounds__(256) void pass2b_stage1(const float* __restrict__ psum,
                                                     const float* __restrict__ pssq,
                                                     double* __restrict__ p2sum,
                                                     double* __restrict__ p2ssq,
                                                     int nblocks) {
    const int t = threadIdx.x;
    const int c = t & 63, s = t >> 6;
    double sum = 0.0, ssq = 0.0;
    for (int i = blockIdx.x * 4 + s; i < nblocks; i += 32 * 4) {
        sum += (double)psum[(size_t)i * 64 + c];
        ssq += (double)pssq[(size_t)i * 64 + c];
    }
    __shared__ double ds_[4][64], dq_[4][64];
    ds_[s][c] = sum;
    dq_[s][c] = ssq;
    __syncthreads();
    if (s == 0) {
        p2sum[(size_t)blockIdx.x * 64 + c] = ds_[0][c] + ds_[1][c] + ds_[2][c] + ds_[3][c];
        p2ssq[(size_t)blockIdx.x * 64 + c] = dq_[0][c] + dq_[1][c] + dq_[2][c] + dq_[3][c];
    }
}

// ---------------------------------------------------------------------------
// Pass 2b stage 2: single block -> scale/shift.
// ---------------------------------------------------------------------------
__global__ __launch_bounds__(256) void pass2b_stage2(const double* __restrict__ p2sum,
                                                     const double* __restrict__ p2ssq,
                                                     const float* __restrict__ gamma,
                                                     const float* __restrict__ beta,
                                                     float* __restrict__ scsh) {
    const int t = threadIdx.x;
    const int c = t & 63, s = t >> 6;
    double sum = 0.0, ssq = 0.0;
    for (int i = s; i < 32; i += 4) {
        sum += p2sum[(size_t)i * 64 + c];
        ssq += p2ssq[(size_t)i * 64 + c];
    }
    __shared__ double ds_[4][64], dq_[4][64];
    ds_[s][c] = sum;
    dq_[s][c] = ssq;
    __syncthreads();
    if (s == 0) {
        double S = ds_[0][c] + ds_[1][c] + ds_[2][c] + ds_[3][c];
        double Q = dq_[0][c] + dq_[1][c] + dq_[2][c] + dq_[3][c];
        const double cnt = (double)BB * NN * KK;
        double mean = S / cnt;
        double var  = Q / cnt - mean * mean;
        float scale = (float)((double)gamma[c] / sqrt(var + BN_EPS));
        float shift = (float)((double)beta[c] - mean * (double)scale);
        scsh[c]      = scale;
        scsh[64 + c] = shift;
    }
}

// ---------------------------------------------------------------------------
// Pass 4: out[b][o][n] = relu(scale[o]*hsel + shift[o]); hmm rows are fp16.
// ---------------------------------------------------------------------------
__global__ __launch_bounds__(256) void pass4_out(const __half* __restrict__ hmm,
                                                 const float* __restrict__ scsh,
                                                 float* __restrict__ out) {
    const int b  = blockIdx.x & 7;
    const int n0 = (blockIdx.x >> 3) * 64;
    const int w    = threadIdx.x >> 6;
    const int lane = threadIdx.x & 63;

    __shared__ float ts[64][65];
    const float sc = scsh[lane];
    const float sh = scsh[64 + lane];

    for (int i = 0; i < 16; ++i) {
        const int j = w + 4 * i;
        const __half* row = hmm + ((size_t)b * NN + n0 + j) * 128;
        float hv = (sc >= 0.f) ? __half2float(row[lane])
                               : __half2float(row[64 + lane]);
        ts[j][lane] = fmaxf(0.f, fmaf(sc, hv, sh));
    }
    __syncthreads();
    for (int i = 0; i < 16; ++i) {
        const int o = w + 4 * i;
        out[((size_t)b * COUT + o) * NN + n0 + lane] = ts[lane][o];
    }
}

// ---------------------------------------------------------------------------
extern "C" void kernel_launch(void* const* d_in, const int* in_sizes, int n_in,
                              void* d_out, int out_size, void* d_ws, size_t ws_size,
                              hipStream_t stream) {
    const float* x     = (const float*)d_in[0]; // [B, C, N, 1]
    const float* wgt   = (const float*)d_in[1]; // [64, 128]
    const float* gamma = (const float*)d_in[2]; // [64]
    const float* beta  = (const float*)d_in[3]; // [64]
    const int*   eidx  = (const int*)d_in[4];   // [2, B, N, K]
    float* out = (float*)d_out;                 // [B, 64, N]

    // workspace layout
    float*  yc   = (float*)d_ws;                          // B*N*128 floats (32 MB)
    __half* hmm  = (__half*)(yc + (size_t)BB * NN * 128); // B*N*128 halves (16 MB)
    float*  psum = (float*)(hmm + (size_t)BB * NN * 128); // 2048*64 floats
    float*  pssq = psum + (size_t)(BB * (NN / 32)) * 64;  // 2048*64 floats
    float*  scsh = pssq + (size_t)(BB * (NN / 32)) * 64;  // 128 floats
    double* p2sum = (double*)(scsh + 128 + 32);           // 32*64 doubles
    double* p2ssq = p2sum + 32 * 64;                      // 32*64 doubles

    const int nblk2 = BB * (NN / 32); // 2048

    hipLaunchKernelGGL(pass1_yc, dim3(BB * (NN / 64)), dim3(256), 0, stream,
                       x, wgt, yc);
    hipLaunchKernelGGL(pass2_gather, dim3(nblk2), dim3(256), 0, stream,
                       yc, eidx, hmm, psum, pssq);
    hipLaunchKernelGGL(pass2b_stage1, dim3(32), dim3(256), 0, stream,
                       psum, pssq, p2sum, p2ssq, nblk2);
    hipLaunchKernelGGL(pass2b_stage2, dim3(1), dim3(256), 0, stream,
                       p2sum, p2ssq, gamma, beta, scsh);
    hipLaunchKernelGGL(pass4_out, dim3(BB * (NN / 64)), dim3(256), 0, stream,
                       hmm, scsh, out);
}